// Round 2
// baseline (624.315 us; speedup 1.0000x reference)
//
#include <hip/hip_runtime.h>
#include <math.h>

typedef float f32x4 __attribute__((ext_vector_type(4)));

// Problem constants: B=64, N=17, T=512, C=64, H=4, DK=16
#define SLAB 32768           // per-(b,n) elems = T*C
#define BSLAB 557056         // per-b elems = N*T*C

__device__ __forceinline__ float gelu_exact(float x) {
  return 0.5f * x * (1.0f + erff(x * 0.7071067811865475f));
}

// ---------------------------------------------------------------------------
// K1: H[r,o] = sum_c X[r,c] * W[o,c]   fp32, M=557056, K=N=64.
// Block = 32 rows x 64 cols, 256 threads; thread = 1 row, 8 cols (stride 8).
// W staged in LDS pitch 68 (c0*68%32 = 4*c0 -> 8 distinct bank-quads, 8-lane
// broadcast, conflict-free).
// ---------------------------------------------------------------------------
__global__ __launch_bounds__(256) void k_gemm(const float* __restrict__ X,
                                              const float* __restrict__ W,
                                              float* __restrict__ H) {
  __shared__ float Ws[64 * 68];
  const int tid = threadIdx.x;
  for (int i = tid; i < 1024; i += 256) {
    int o = i >> 4, k4 = i & 15;
    *(f32x4*)(Ws + o * 68 + k4 * 4) = *(const f32x4*)(W + o * 64 + k4 * 4);
  }
  __syncthreads();

  const long row = (long)blockIdx.x * 32 + (tid >> 3);
  const int c0 = tid & 7;
  const float* xr = X + row * 64;
  float acc[8] = {0, 0, 0, 0, 0, 0, 0, 0};
  for (int k4 = 0; k4 < 16; ++k4) {
    f32x4 xv = *(const f32x4*)(xr + k4 * 4);
#pragma unroll
    for (int j = 0; j < 8; ++j) {
      f32x4 wv = *(const f32x4*)(Ws + (c0 + 8 * j) * 68 + k4 * 4);
      acc[j] += xv.x * wv.x + xv.y * wv.y + xv.z * wv.z + xv.w * wv.w;
    }
  }
  float* hr = H + row * 64;
#pragma unroll
  for (int j = 0; j < 8; ++j) hr[c0 + 8 * j] = acc[j];
}

// ---------------------------------------------------------------------------
// K2: GAT attention. One block per bt = b*512 + t.
// Reads H[b,:,t,:] (ws) and x[b,:,t,:]; writes g = h*scale + h0 IN-PLACE over
// H (disjoint slices), and the permuted residual resP into d_out:
//   resP[b, m/64, t, m%64] = x[b, m%17, t, m/17],  m = n*64+c.
// ---------------------------------------------------------------------------
__global__ __launch_bounds__(256) void k_gat(float* __restrict__ Hg,
                                             const float* __restrict__ X,
                                             const int* __restrict__ adj,
                                             const float* __restrict__ avec,
                                             float* __restrict__ resP) {
  const int bt = blockIdx.x;
  const int b = bt >> 9, t = bt & 511;
  const int tid = threadIdx.x;

  __shared__ float hs[17 * 65];
  __shared__ float h0s[17 * 65];
  __shared__ float sv[17 * 4], tv[17 * 4], scalev[17 * 4];
  __shared__ float alpha[17 * 17 * 4];
  __shared__ float av[32];
  __shared__ int adjs[17 * 17];

  const long base = (long)b * BSLAB + (long)t * 64;

  for (int idx = tid; idx < 1088; idx += 256) {
    int n = idx >> 6, c = idx & 63;
    long a = base + (long)n * SLAB + c;
    hs[n * 65 + c] = Hg[a];
    h0s[n * 65 + c] = X[a];
  }
  if (tid < 32) av[tid] = avec[tid];
  for (int idx = tid; idx < 289; idx += 256) adjs[idx] = adj[b * 289 + idx];
  __syncthreads();

  if (tid < 68) {
    int n = tid >> 2, h = tid & 3;
    float s = 0.f, tt = 0.f;
#pragma unroll
    for (int d = 0; d < 16; ++d) {
      float hv = hs[n * 65 + h * 16 + d];
      s += hv * av[d];
      tt += hv * av[16 + d];
    }
    sv[n * 4 + h] = s;
    tv[n * 4 + h] = tt;
  }
  __syncthreads();

  if (tid < 68) {
    int i = tid >> 2, h = tid & 3;
    float si = sv[i * 4 + h];
    float e[17];
    float mx = -3.4e38f;
#pragma unroll
    for (int j = 0; j < 17; ++j) {
      float v = si + tv[j * 4 + h];
      v = (v >= 0.f) ? v : 0.2f * v;           // leaky_relu(0.2)
      if (adjs[i * 17 + j] == 0) v += -1e9f;   // mask bias after lrelu
      e[j] = v;
      mx = fmaxf(mx, v);
    }
    float sum = 0.f;
#pragma unroll
    for (int j = 0; j < 17; ++j) { float p = expf(e[j] - mx); e[j] = p; sum += p; }
    float inv = 1.0f / sum;
#pragma unroll
    for (int j = 0; j < 17; ++j) alpha[(i * 17 + j) * 4 + h] = e[j] * inv;
  }
  __syncthreads();

  if (tid < 68) {
    int j = tid >> 2, h = tid & 3;
    float sc = 0.f;
#pragma unroll
    for (int i = 0; i < 17; ++i) sc += alpha[(i * 17 + j) * 4 + h];
    scalev[j * 4 + h] = sc;
  }
  __syncthreads();

  for (int idx = tid; idx < 1088; idx += 256) {
    int n = idx >> 6, c = idx & 63;
    long a = base + (long)n * SLAB + c;
    Hg[a] = hs[n * 65 + c] * scalev[n * 4 + (c >> 4)] + h0s[n * 65 + c];
    resP[a] = h0s[(idx % 17) * 65 + (idx / 17)];
  }
}

// ---------------------------------------------------------------------------
// K3: TCN (2x causal depthwise conv + eval-BN + exact GELU) + transpose +
// residual add. One block per (b,n). g's per-(b,n) flat [T,C] block IS the
// conv layout [c'=idx>>9][t'=idx&511]. Processed in two t-halves of 256
// (LDS 64x257 fp32 = 64.3 KB -> 2 blocks/CU). Thread (cc=tid>>2, q=tid&3)
// convs t' in [q*128, q*128+128) during half q>>1 (lead-in from global g).
// resP lives in d_out; final out overwrites it same-thread same-address.
// ---------------------------------------------------------------------------
__global__ __launch_bounds__(256) void k_tcn(const float* __restrict__ g,
                                             const float* __restrict__ w1,
                                             const float* __restrict__ gamma1,
                                             const float* __restrict__ beta1,
                                             const float* __restrict__ w2,
                                             const float* __restrict__ gamma2,
                                             const float* __restrict__ beta2,
                                             float* __restrict__ out) {
  const int bn = blockIdx.x;
  const int tid = threadIdx.x;
  const int cc = tid >> 2, q = tid & 3;

  __shared__ float L[64 * 257];

  const long gbase = (long)bn * SLAB + cc * 512;
  const long obase = (long)bn * SLAB;

  const float bnmul = 0.9999950000374997f;  // 1/sqrt(1+1e-5)
  const float w10 = w1[cc * 3 + 0], w11 = w1[cc * 3 + 1], w12 = w1[cc * 3 + 2];
  const float w20 = w2[cc * 3 + 0], w21 = w2[cc * 3 + 1], w22 = w2[cc * 3 + 2];
  const float bs1 = gamma1[cc] * bnmul, bb1 = beta1[cc];
  const float bs2 = gamma2[cc] * bnmul, bb2 = beta2[cc];

  const int t0 = q * 128;

  for (int h = 0; h < 2; ++h) {
    if ((q >> 1) == h) {
      float gm1 = 0.f, gm2 = 0.f;
      float zm1 = 0.f, zm2 = 0.f, zm3 = 0.f, zm4 = 0.f;
      if (q > 0) {
        float gg[6];
#pragma unroll
        for (int k = 0; k < 6; ++k) gg[k] = g[gbase + (t0 - 6 + k)];
        zm4 = gelu_exact((w10 * gg[0] + w11 * gg[1] + w12 * gg[2]) * bs1 + bb1);
        zm3 = gelu_exact((w10 * gg[1] + w11 * gg[2] + w12 * gg[3]) * bs1 + bb1);
        zm2 = gelu_exact((w10 * gg[2] + w11 * gg[3] + w12 * gg[4]) * bs1 + bb1);
        zm1 = gelu_exact((w10 * gg[3] + w11 * gg[4] + w12 * gg[5]) * bs1 + bb1);
        gm2 = gg[4];
        gm1 = gg[5];
      }
      for (int blk = 0; blk < 32; ++blk) {
        f32x4 gv4 = *(const f32x4*)(g + gbase + t0 + blk * 4);
#pragma unroll
        for (int j = 0; j < 4; ++j) {
          float gv = gv4[j];
          float z = gelu_exact((w10 * gm2 + w11 * gm1 + w12 * gv) * bs1 + bb1);
          float y = gelu_exact((w20 * zm4 + w21 * zm2 + w22 * z) * bs2 + bb2);
          L[cc * 257 + (t0 + blk * 4 + j - h * 256)] = y;
          gm2 = gm1; gm1 = gv;
          zm4 = zm3; zm3 = zm2; zm2 = zm1; zm1 = z;
        }
      }
    }
    __syncthreads();

    // transpose + residual for out flat range [h*16384, h*16384+16384)
    for (int k = 0; k < 16; ++k) {
      int f4 = h * 4096 + tid + k * 256;
      int flat = f4 * 4;
      int t = flat >> 6, c0 = flat & 63;
      f32x4 r4 = *(const f32x4*)(out + obase + flat);
      f32x4 o4;
#pragma unroll
      for (int j = 0; j < 4; ++j)
        o4[j] = L[(c0 + j) * 257 + (t - h * 256)] + r4[j];
      *(f32x4*)(out + obase + flat) = o4;
    }
    __syncthreads();
  }
}

// ---------------------------------------------------------------------------
extern "C" void kernel_launch(void* const* d_in, const int* in_sizes, int n_in,
                              void* d_out, int out_size, void* d_ws, size_t ws_size,
                              hipStream_t stream) {
  const float* x = (const float*)d_in[0];
  const int* adj = (const int*)d_in[1];
  const float* W = (const float*)d_in[2];
  const float* avec = (const float*)d_in[3];
  const float* w1 = (const float*)d_in[4];
  const float* gamma1 = (const float*)d_in[5];
  const float* beta1 = (const float*)d_in[6];
  const float* w2 = (const float*)d_in[7];
  const float* gamma2 = (const float*)d_in[8];
  const float* beta2 = (const float*)d_in[9];

  float* H = (float*)d_ws;       // 35,651,584 fp32 = 142.6 MB scratch (H -> g)
  float* out = (float*)d_out;    // resP written by K2, consumed in-place by K3

  k_gemm<<<17408, 256, 0, stream>>>(x, W, H);
  k_gat<<<32768, 256, 0, stream>>>(H, x, adj, avec, out);
  k_tcn<<<1088, 256, 0, stream>>>(H, w1, gamma1, beta1, w2, gamma2, beta2, out);
}